// Round 1
// baseline (345.655 us; speedup 1.0000x reference)
//
#include <hip/hip_runtime.h>

// CenterLoss: mean over B rows of clip(||x_b - centers[label_b]||^2, 1e-12, 1e12)
// labels are exact one-hot fp32 rows -> dense dot == row gather (bit-exact).
//
// R1: 8192 same-address atomics serialized at the TCC (110 us kernel).
// R2: per-block partial stores + 1-block reduce -> 115.9 us total. ~95 us is
//     the harness's fixed 268 MB d_ws re-poison + reset; our kernels ~20 us
//     vs a ~15.5 us mandatory-fetch floor (98 MB @ 6.3 TB/s).
// R4: wave-per-row + nontemporal loads REGRESSED (122.3 us).
// R5: revert to R2.
// R6 (this): fuse the reduce into the main kernel via last-block-done ticket.
//     Saves the dependent reduce launch (~1-2 us gap) + its ~2 us execution;
//     costs a 4-byte memset (ticket init; d_ws is re-poisoned every iter).
//     Cross-XCD visibility: partials stored with agent-scope write-through
//     atomic stores; ticket RMW is release; last block issues an agent
//     acquire fence (L1/L2 invalidate) before plain float4 re-reads.
//     Reduction arithmetic order is bit-identical to R2's reduce_kernel.

#define BATCH 8192
#define NUM_CLASSES 751
#define FEAT_DIM 2048

__global__ __launch_bounds__(256) void center_loss_fused(
    const float* __restrict__ x,
    const float* __restrict__ labels,
    const float* __restrict__ centers,
    float* __restrict__ partials,
    unsigned int* __restrict__ ticket,
    float* __restrict__ out)
{
    const int row = blockIdx.x;
    const int tid = threadIdx.x;

    // ---- Prefetch x row (independent of labels) to overlap HBM latency ----
    const float4* __restrict__ xrow = (const float4*)(x + (size_t)row * FEAT_DIM);
    float4 xv0 = xrow[tid];
    float4 xv1 = xrow[tid + 256];

    // ---- Find the one-hot index (coalesced scan of 751 floats) ----
    __shared__ int s_idx;
    const float* lrow = labels + (size_t)row * NUM_CLASSES;
    #pragma unroll
    for (int c = tid; c < NUM_CLASSES; c += 256) {
        if (lrow[c] > 0.5f) s_idx = c;   // exactly one thread writes
    }
    __syncthreads();
    const int idx = s_idx;

    // ---- Gather center row and accumulate squared distance ----
    const float4* __restrict__ crow = (const float4*)(centers + (size_t)idx * FEAT_DIM);
    float4 cv0 = crow[tid];
    float4 cv1 = crow[tid + 256];

    float dx = xv0.x - cv0.x, dy = xv0.y - cv0.y, dz = xv0.z - cv0.z, dw = xv0.w - cv0.w;
    float sum = dx * dx + dy * dy + dz * dz + dw * dw;
    dx = xv1.x - cv1.x; dy = xv1.y - cv1.y; dz = xv1.z - cv1.z; dw = xv1.w - cv1.w;
    sum += dx * dx + dy * dy + dz * dz + dw * dw;

    // ---- wave-64 shuffle reduction ----
    #pragma unroll
    for (int off = 32; off > 0; off >>= 1)
        sum += __shfl_down(sum, off, 64);

    __shared__ float s_part[4];
    __shared__ int s_last;
    const int wave = tid >> 6;
    const int lane = tid & 63;
    if (lane == 0) s_part[wave] = sum;
    __syncthreads();

    if (tid == 0) {
        float ps = s_part[0] + s_part[1] + s_part[2] + s_part[3];
        ps = fminf(fmaxf(ps, 1e-12f), 1e12f);   // clip
        // Agent-scope write-through store: lands at the coherent point, so
        // the reducing block (possibly another XCD) can see it after its
        // acquire fence without depending on our XCD's L2.
        __hip_atomic_store(&partials[row], ps, __ATOMIC_RELAXED,
                           __HIP_MEMORY_SCOPE_AGENT);
        // Release RMW: orders the partial store before the ticket bump.
        unsigned int old = __hip_atomic_fetch_add(
            ticket, 1u, __ATOMIC_ACQ_REL, __HIP_MEMORY_SCOPE_AGENT);
        s_last = (old == (unsigned int)(BATCH - 1));
    }
    __syncthreads();

    if (!s_last) return;   // uniform per block — no divergent sync below

    // ---- last-arriving block: deterministic reduce, identical order to R2 ----
    // Acquire fence pairs with every block's release RMW: invalidates
    // L1/L2 so the plain vector loads below observe all partials stores.
    __builtin_amdgcn_fence(__ATOMIC_ACQUIRE, "agent");

    const float4* __restrict__ p4 = (const float4*)partials;  // 2048 float4s
    float total = 0.0f;
    #pragma unroll
    for (int k = 0; k < 8; ++k) {
        float4 v = p4[tid + 256 * k];
        total += v.x + v.y + v.z + v.w;
    }

    #pragma unroll
    for (int off = 32; off > 0; off >>= 1)
        total += __shfl_down(total, off, 64);

    __shared__ float s_red[4];
    if (lane == 0) s_red[wave] = total;
    __syncthreads();

    if (tid == 0) {
        float t = s_red[0] + s_red[1] + s_red[2] + s_red[3];
        out[0] = t * (1.0f / (float)BATCH);
    }
}

extern "C" void kernel_launch(void* const* d_in, const int* in_sizes, int n_in,
                              void* d_out, int out_size, void* d_ws, size_t ws_size,
                              hipStream_t stream)
{
    const float* x       = (const float*)d_in[0];
    const float* labels  = (const float*)d_in[1];
    const float* centers = (const float*)d_in[2];
    float* out      = (float*)d_out;
    float* partials = (float*)d_ws;                    // 8192 floats
    unsigned int* ticket =
        (unsigned int*)((char*)d_ws + BATCH * sizeof(float));

    // d_ws is re-poisoned by the harness every iteration -> ticket must be
    // zeroed each launch. 4-byte memset, graph-capturable.
    hipMemsetAsync(ticket, 0, sizeof(unsigned int), stream);

    center_loss_fused<<<BATCH, 256, 0, stream>>>(
        x, labels, centers, partials, ticket, out);
}

// Round 2
// 114.451 us; speedup vs baseline: 3.0201x; 3.0201x over previous
//
#include <hip/hip_runtime.h>

// CenterLoss: mean over B rows of clip(||x_b - centers[label_b]||^2, 1e-12, 1e12)
// labels are exact one-hot fp32 rows -> dense dot == row gather (bit-exact).
//
// R1: 8192 same-address atomics serialized at the TCC (110 us kernel).
// R2: per-block partial stores + 1-block reduce -> 115.9 us total. ~95 us is
//     the harness's fixed 268 MB d_ws re-poison + reset; our kernels ~20 us
//     vs a ~15.5 us mandatory-fetch floor (98 MB @ 6.3 TB/s).
// R4: wave-per-row + nontemporal loads REGRESSED (122.3 us).
// R5: revert to R2 (measured best).
// R6: fused last-block reduce via agent-scope ACQ_REL ticket REGRESSED HARD
//     (345.7 us; kernel 273 us @ 264 GB/s, VALUBusy 1.5%). Per-block
//     agent-scope release forces an L2 writeback on non-coherent per-XCD
//     L2s -> 8192 serialized L2 drains. Kernel boundary IS the cheap
//     release on CDNA4; never per-block device-scope release.
// R7 (this): R2 structure restored verbatim + early-exit label scan.
//     Index uniform in [0,751) -> chunked 256-float scan with block-wide
//     exit reads avg ~501 floats/row instead of 751: -8.2 MB labels
//     traffic (~-1.3 us at BW-bound). Double barrier per chunk avoids the
//     s_idx read/next-write race (divergent break = deadlock).

#define BATCH 8192
#define NUM_CLASSES 751
#define FEAT_DIM 2048

__global__ __launch_bounds__(256) void center_loss_kernel(
    const float* __restrict__ x,
    const float* __restrict__ labels,
    const float* __restrict__ centers,
    float* __restrict__ partials)
{
    const int row = blockIdx.x;
    const int tid = threadIdx.x;

    // ---- Prefetch x row (independent of labels) to overlap HBM latency ----
    const float4* __restrict__ xrow = (const float4*)(x + (size_t)row * FEAT_DIM);
    float4 xv0 = xrow[tid];
    float4 xv1 = xrow[tid + 256];

    // ---- Find the one-hot index: chunked scan with block-wide early exit.
    // Avg chunks read = 1.98 of 3 -> saves ~33% of label HBM traffic.
    __shared__ int s_idx;
    if (tid == 0) s_idx = -1;
    __syncthreads();

    const float* lrow = labels + (size_t)row * NUM_CLASSES;
    int idx = -1;
    #pragma unroll
    for (int k = 0; k < 3; ++k) {
        const int c = k * 256 + tid;
        if (c < NUM_CLASSES && lrow[c] > 0.5f) s_idx = c;  // one thread writes
        __syncthreads();
        idx = s_idx;
        __syncthreads();          // protect reads from next-chunk writes
        if (idx >= 0) break;      // uniform: s_idx identical across block
    }

    // ---- Gather center row and accumulate squared distance ----
    const float4* __restrict__ crow = (const float4*)(centers + (size_t)idx * FEAT_DIM);
    float4 cv0 = crow[tid];
    float4 cv1 = crow[tid + 256];

    float dx = xv0.x - cv0.x, dy = xv0.y - cv0.y, dz = xv0.z - cv0.z, dw = xv0.w - cv0.w;
    float sum = dx * dx + dy * dy + dz * dz + dw * dw;
    dx = xv1.x - cv1.x; dy = xv1.y - cv1.y; dz = xv1.z - cv1.z; dw = xv1.w - cv1.w;
    sum += dx * dx + dy * dy + dz * dz + dw * dw;

    // ---- wave-64 shuffle reduction ----
    #pragma unroll
    for (int off = 32; off > 0; off >>= 1)
        sum += __shfl_down(sum, off, 64);

    __shared__ float s_part[4];
    const int wave = tid >> 6;
    const int lane = tid & 63;
    if (lane == 0) s_part[wave] = sum;
    __syncthreads();

    if (tid == 0) {
        float ps = s_part[0] + s_part[1] + s_part[2] + s_part[3];
        ps = fminf(fmaxf(ps, 1e-12f), 1e12f);   // clip
        partials[row] = ps;                      // deterministic store, no atomic
    }
}

// Reduce 8192 partials (32 KB, L2-hot) -> mean. One block, 256 threads.
__global__ __launch_bounds__(256) void reduce_kernel(
    const float* __restrict__ partials,
    float* __restrict__ out)
{
    const int tid = threadIdx.x;
    const float4* __restrict__ p4 = (const float4*)partials;  // 2048 float4s

    float sum = 0.0f;
    #pragma unroll
    for (int k = 0; k < 8; ++k) {
        float4 v = p4[tid + 256 * k];
        sum += v.x + v.y + v.z + v.w;
    }

    #pragma unroll
    for (int off = 32; off > 0; off >>= 1)
        sum += __shfl_down(sum, off, 64);

    __shared__ float s_part[4];
    const int wave = tid >> 6;
    const int lane = tid & 63;
    if (lane == 0) s_part[wave] = sum;
    __syncthreads();

    if (tid == 0) {
        float total = s_part[0] + s_part[1] + s_part[2] + s_part[3];
        out[0] = total * (1.0f / (float)BATCH);
    }
}

extern "C" void kernel_launch(void* const* d_in, const int* in_sizes, int n_in,
                              void* d_out, int out_size, void* d_ws, size_t ws_size,
                              hipStream_t stream)
{
    const float* x       = (const float*)d_in[0];
    const float* labels  = (const float*)d_in[1];
    const float* centers = (const float*)d_in[2];
    float* out      = (float*)d_out;
    float* partials = (float*)d_ws;   // 8192 floats, every slot overwritten

    center_loss_kernel<<<BATCH, 256, 0, stream>>>(x, labels, centers, partials);
    reduce_kernel<<<1, 256, 0, stream>>>(partials, out);
}